// Round 1
// baseline (468.393 us; speedup 1.0000x reference)
//
#include <hip/hip_runtime.h>

// Problem constants
constexpr int Bb = 8, Ll = 2048, Ww = 1024, Kk = 5, Gg = 2, Ci = 512, Co = 512;
constexpr int BL = Bb * Ll;          // 16384
constexpr int KDIM = Ci * Kk;        // 2560

typedef short bf16x8 __attribute__((ext_vector_type(8)));
typedef float f32x4  __attribute__((ext_vector_type(4)));

// ---------- bf16 helpers (RNE) ----------
__device__ inline unsigned short f2bf(float f) {
    union { float f; unsigned u; } v; v.f = f;
    unsigned u = v.u;
    unsigned r = (u + 0x7fffu + ((u >> 16) & 1u)) >> 16;
    return (unsigned short)r;
}
__device__ inline float bf2f(unsigned short h) {
    union { unsigned u; float f; } v; v.u = ((unsigned)h) << 16;
    return v.f;
}
__device__ inline unsigned lerp2(unsigned a, unsigned b, float w0, float w1) {
    float a0 = bf2f((unsigned short)(a & 0xffffu));
    float a1 = bf2f((unsigned short)(a >> 16));
    float b0 = bf2f((unsigned short)(b & 0xffffu));
    float b1 = bf2f((unsigned short)(b >> 16));
    float r0 = w0 * a0 + w1 * b0;
    float r1 = w0 * a1 + w1 * b1;
    return (unsigned)f2bf(r0) | (((unsigned)f2bf(r1)) << 16);
}

// ---------- kernel 0: mask dtype detect + expand to float (1=valid, 0=padded) ----------
__global__ void mask_expand_kernel(const void* __restrict__ mraw, float* __restrict__ maskf) {
    const unsigned char* mb = (const unsigned char*)mraw;
    const unsigned* mw = (const unsigned*)mraw;
    __shared__ int s_nonint, s_notf, s_hasf;
    if (threadIdx.x == 0) { s_nonint = 0; s_notf = 0; s_hasf = 0; }
    __syncthreads();
    int nonint = 0, notf = 0, hasf = 0;
    for (int i = threadIdx.x; i < BL; i += blockDim.x) {
        unsigned char c = mb[i];                 // first BL bytes are safe under all dtypes
        if ((i & 3) && c) nonint = 1;
    }
    for (int i = threadIdx.x; i < BL / 4; i += blockDim.x) {
        unsigned w = mw[i];
        if (w == 0x3f800000u) hasf = 1; else if (w) notf = 1;
    }
    if (nonint) atomicOr(&s_nonint, 1);
    if (notf)   atomicOr(&s_notf, 1);
    if (hasf)   atomicOr(&s_hasf, 1);
    __syncthreads();
    int is_f32  = (!s_notf) && s_hasf;           // words are {0, 1.0f}
    int is_bool = (!is_f32) && s_nonint;         // 1-byte bools
    for (int i = threadIdx.x; i < BL; i += blockDim.x) {
        int masked;
        if (is_bool) masked = (mb[i] != 0);
        else         masked = (mw[i] != 0u);     // int32 or float32: nonzero pattern == True
        maskf[i] = masked ? 0.0f : 1.0f;
    }
}

// ---------- kernel 1a: conv_w fp32 [go][c][k] -> bf16 [go][k*512+c] ----------
__global__ void wconv_kernel(const float* __restrict__ conv_w, unsigned short* __restrict__ w_bf) {
    int go = blockIdx.x;                          // g*512+o, 0..1023
    const float* src = conv_w + (size_t)go * (Ci * Kk);
    unsigned short* dst = w_bf + (size_t)go * KDIM;
    for (int kk = threadIdx.x; kk < KDIM; kk += blockDim.x) {
        int k = kk >> 9, c = kk & 511;
        dst[kk] = f2bf(src[c * Kk + k]);
    }
}

// ---------- kernel 1b: offsets (tanh(x@w_off)+pos -> idx/weights) + x -> bf16 ----------
__global__ __launch_bounds__(256) void offsets_kernel(
    const float* __restrict__ x, const float* __restrict__ w_off, const float* __restrict__ b_off,
    unsigned short* __restrict__ x_bf, int* __restrict__ idx0, int* __restrict__ idx1,
    float* __restrict__ w0a, float* __restrict__ w1a)
{
    int bl = blockIdx.x;
    int l = bl & (Ll - 1);
    int tid = threadIdx.x;
    const float* xr = x + (size_t)bl * Ww;
    float4 v = *(const float4*)(xr + tid * 4);
    ushort4 xb4 = { f2bf(v.x), f2bf(v.y), f2bf(v.z), f2bf(v.w) };
    *(ushort4*)(x_bf + (size_t)bl * Ww + tid * 4) = xb4;

    float acc[5] = {0.f, 0.f, 0.f, 0.f, 0.f};
    int c = tid * 4;
    const float* vv = (const float*)&v;
    #pragma unroll
    for (int j = 0; j < 4; j++) {
        float xv = vv[j];
        #pragma unroll
        for (int k = 0; k < 5; k++) acc[k] += xv * w_off[(c + j) * 5 + k];
    }
    #pragma unroll
    for (int k = 0; k < 5; k++)
        for (int off = 32; off; off >>= 1) acc[k] += __shfl_down(acc[k], off);

    __shared__ float red[4][5];
    int wave = tid >> 6, lane = tid & 63;
    if (lane == 0) {
        #pragma unroll
        for (int k = 0; k < 5; k++) red[wave][k] = acc[k];
    }
    __syncthreads();
    if (tid < 5) {
        int k = tid;
        float s = red[0][k] + red[1][k] + red[2][k] + red[3][k] + b_off[k];
        float offv = tanhf(s) * 2.0f;
        float pos = (float)l + (float)(k - 2) + offv;
        float p0 = floorf(pos);
        float frac = pos - p0;
        int i0 = (int)p0;
        int i1 = i0 + 1;
        int v0 = (i0 >= 0) && (i0 < Ll);
        int v1 = (i1 >= 0) && (i1 < Ll);
        idx0[bl * 5 + k] = min(max(i0, 0), Ll - 1);
        idx1[bl * 5 + k] = min(max(i1, 0), Ll - 1);
        w0a[bl * 5 + k] = v0 ? (1.0f - frac) : 0.0f;
        w1a[bl * 5 + k] = v1 ? frac : 0.0f;
    }
}

// ---------- kernel 2: fused deform-gather + grouped GEMM (bf16 MFMA) ----------
// C[m, n] = sum_kk A[m,kk] * W[n,kk], kk = k*512+c; A built on the fly from x_bf.
__global__ __launch_bounds__(256) void gemm_kernel(
    const unsigned short* __restrict__ x_bf, const unsigned short* __restrict__ w_bf,
    const int* __restrict__ idx0, const int* __restrict__ idx1,
    const float* __restrict__ w0a, const float* __restrict__ w1a,
    const float* __restrict__ conv_b, unsigned short* __restrict__ h)
{
    __shared__ unsigned short Als[128 * 40];   // [m][32] padded to 40 elems (80B rows)
    __shared__ unsigned short Bls[128 * 40];   // [n][32] padded

    const int tid = threadIdx.x;
    const int ntile = blockIdx.x;              // 0..7 (128 output channels each)
    const int mtile = blockIdx.y;              // 0..127 (128 rows each, within one b)
    const int bl0 = mtile * 128;
    const int b = bl0 >> 11;
    const int g = ntile >> 2;
    const int ocol0 = ntile * 128;             // global out channel base == w_bf row base
    const int gch0 = g << 9;                   // input channel base of this group

    const int wave = tid >> 6, lane = tid & 63;
    const int wr = (wave >> 1) * 64, wc = (wave & 1) * 64;
    const int l15 = lane & 15, l4 = lane >> 4;

    const int am = tid >> 1, ah = tid & 1;     // 2 threads per row, 16 elems each
    const int abl = bl0 + am;
    const unsigned short* xb = x_bf + ((size_t)b * Ll) * Ww + gch0 + ah * 16;
    const unsigned short* wrow = w_bf + (size_t)(ocol0 + am) * KDIM + ah * 16;

    f32x4 acc[4][4];
    #pragma unroll
    for (int i = 0; i < 4; i++)
        #pragma unroll
        for (int j = 0; j < 4; j++) acc[i][j] = (f32x4){0.f, 0.f, 0.f, 0.f};

    for (int k = 0; k < 5; k++) {
        const int sidx = abl * 5 + k;
        const int i0 = idx0[sidx], i1 = idx1[sidx];
        const float w0 = w0a[sidx], w1 = w1a[sidx];
        const unsigned short* r0 = xb + (size_t)i0 * Ww;
        const unsigned short* r1 = xb + (size_t)i1 * Ww;
        const unsigned short* wk = wrow + k * 512;
        for (int cs = 0; cs < 16; cs++) {
            const int c0 = cs * 32;
            // global loads (before barrier for latency overlap)
            uint4 x0a = *(const uint4*)(r0 + c0);
            uint4 x0b = *(const uint4*)(r0 + c0 + 8);
            uint4 x1a = *(const uint4*)(r1 + c0);
            uint4 x1b = *(const uint4*)(r1 + c0 + 8);
            uint4 wva = *(const uint4*)(wk + c0);
            uint4 wvb = *(const uint4*)(wk + c0 + 8);
            uint4 oa, ob;
            oa.x = lerp2(x0a.x, x1a.x, w0, w1);
            oa.y = lerp2(x0a.y, x1a.y, w0, w1);
            oa.z = lerp2(x0a.z, x1a.z, w0, w1);
            oa.w = lerp2(x0a.w, x1a.w, w0, w1);
            ob.x = lerp2(x0b.x, x1b.x, w0, w1);
            ob.y = lerp2(x0b.y, x1b.y, w0, w1);
            ob.z = lerp2(x0b.z, x1b.z, w0, w1);
            ob.w = lerp2(x0b.w, x1b.w, w0, w1);
            __syncthreads();  // prev iter's ds_reads done
            *(uint4*)&Als[am * 40 + ah * 16]     = oa;
            *(uint4*)&Als[am * 40 + ah * 16 + 8] = ob;
            *(uint4*)&Bls[am * 40 + ah * 16]     = wva;
            *(uint4*)&Bls[am * 40 + ah * 16 + 8] = wvb;
            __syncthreads();
            bf16x8 af[4], bfr[4];
            #pragma unroll
            for (int i = 0; i < 4; i++)
                af[i] = *(const bf16x8*)&Als[(wr + i * 16 + l15) * 40 + l4 * 8];
            #pragma unroll
            for (int j = 0; j < 4; j++)
                bfr[j] = *(const bf16x8*)&Bls[(wc + j * 16 + l15) * 40 + l4 * 8];
            #pragma unroll
            for (int i = 0; i < 4; i++)
                #pragma unroll
                for (int j = 0; j < 4; j++)
                    acc[i][j] = __builtin_amdgcn_mfma_f32_16x16x32_bf16(af[i], bfr[j], acc[i][j], 0, 0, 0);
        }
    }
    // epilogue: + conv_b, store h (bf16)
    #pragma unroll
    for (int j = 0; j < 4; j++) {
        int col = ocol0 + wc + j * 16 + l15;
        float bias = conv_b[col];
        #pragma unroll
        for (int i = 0; i < 4; i++) {
            int row0 = bl0 + wr + i * 16 + l4 * 4;
            #pragma unroll
            for (int r = 0; r < 4; r++) {
                h[(size_t)(row0 + r) * Ww + col] = f2bf(acc[i][j][r] + bias);
            }
        }
    }
}

// ---------- kernel 3: LayerNorm + masked fill + pooled partial sums ----------
__global__ __launch_bounds__(256) void lnpool_kernel(
    const unsigned short* __restrict__ h, const float* __restrict__ gamma,
    const float* __restrict__ beta, const float* __restrict__ maskf,
    float* __restrict__ pooled)
{
    int b = blockIdx.x >> 4;
    int lc = blockIdx.x & 15;
    int tid = threadIdx.x;
    int wave = tid >> 6, lane = tid & 63;
    __shared__ float red[2][4];
    float g4[4], be4[4], pacc[4] = {0.f, 0.f, 0.f, 0.f};
    #pragma unroll
    for (int j = 0; j < 4; j++) { g4[j] = gamma[tid * 4 + j]; be4[j] = beta[tid * 4 + j]; }

    for (int r = 0; r < 128; r++) {
        int bl = b * Ll + lc * 128 + r;
        float m = maskf[bl];
        if (m == 0.0f) continue;               // uniform across block
        ushort4 hv = *(const ushort4*)(h + (size_t)bl * Ww + tid * 4);
        float v0 = bf2f(hv.x), v1 = bf2f(hv.y), v2 = bf2f(hv.z), v3 = bf2f(hv.w);
        float s1 = v0 + v1 + v2 + v3;
        float s2 = v0 * v0 + v1 * v1 + v2 * v2 + v3 * v3;
        for (int off = 32; off; off >>= 1) {
            s1 += __shfl_down(s1, off);
            s2 += __shfl_down(s2, off);
        }
        __syncthreads();
        if (lane == 0) { red[0][wave] = s1; red[1][wave] = s2; }
        __syncthreads();
        float S1 = red[0][0] + red[0][1] + red[0][2] + red[0][3];
        float S2 = red[1][0] + red[1][1] + red[1][2] + red[1][3];
        float mu = S1 * (1.0f / 1024.0f);
        float var = S2 * (1.0f / 1024.0f) - mu * mu;
        float rstd = rsqrtf(var + 1e-5f);
        pacc[0] += (v0 - mu) * rstd * g4[0] + be4[0];
        pacc[1] += (v1 - mu) * rstd * g4[1] + be4[1];
        pacc[2] += (v2 - mu) * rstd * g4[2] + be4[2];
        pacc[3] += (v3 - mu) * rstd * g4[3] + be4[3];
    }
    #pragma unroll
    for (int j = 0; j < 4; j++) atomicAdd(&pooled[b * Ww + tid * 4 + j], pacc[j]);
}

// ---------- kernel 4: lengths + projection ----------
__global__ void final_kernel(const float* __restrict__ pooled, const float* __restrict__ maskf,
                             const float* __restrict__ proj_w, const float* __restrict__ proj_b,
                             float* __restrict__ out)
{
    int b = blockIdx.x;
    int tid = threadIdx.x;
    float len = 0.f, dot = 0.f;
    for (int l = tid; l < Ll; l += 256) len += maskf[b * Ll + l];
    for (int c = tid; c < Ww; c += 256) dot += pooled[b * Ww + c] * proj_w[c];
    for (int off = 32; off; off >>= 1) {
        len += __shfl_down(len, off);
        dot += __shfl_down(dot, off);
    }
    __shared__ float rl[4], rd[4];
    int wave = tid >> 6, lane = tid & 63;
    if (lane == 0) { rl[wave] = len; rd[wave] = dot; }
    __syncthreads();
    if (tid == 0) {
        float Lt = rl[0] + rl[1] + rl[2] + rl[3];
        float Dt = rd[0] + rd[1] + rd[2] + rd[3];
        out[b] = Dt / fmaxf(Lt, 1.0f) + proj_b[0];
    }
}

// ---------- workspace layout (bytes, all 16B-aligned) ----------
// maskf   @        0  (65536)
// pooled  @    65536  (32768)
// idx0    @    98304  (655360)
// idx1    @   753664  (655360)
// w0a     @  1409024  (655360)
// w1a     @  2064384  (655360)
// w_bf    @  2719744  (5242880)
// x_bf    @  7962624  (33554432)
// h       @ 41517056  (33554432)   -> total 75,071,488 B

extern "C" void kernel_launch(void* const* d_in, const int* in_sizes, int n_in,
                              void* d_out, int out_size, void* d_ws, size_t ws_size,
                              hipStream_t stream)
{
    const float* x      = (const float*)d_in[0];
    const void*  mask   = d_in[1];
    const float* w_off  = (const float*)d_in[2];
    const float* b_off  = (const float*)d_in[3];
    const float* conv_w = (const float*)d_in[4];
    const float* conv_b = (const float*)d_in[5];
    const float* gamma  = (const float*)d_in[6];
    const float* beta   = (const float*)d_in[7];
    const float* proj_w = (const float*)d_in[8];
    const float* proj_b = (const float*)d_in[9];
    float* out = (float*)d_out;

    char* ws = (char*)d_ws;
    float* maskf         = (float*)(ws + 0);
    float* pooled        = (float*)(ws + 65536);
    int*   idx0          = (int*)(ws + 98304);
    int*   idx1          = (int*)(ws + 753664);
    float* w0a           = (float*)(ws + 1409024);
    float* w1a           = (float*)(ws + 2064384);
    unsigned short* w_bf = (unsigned short*)(ws + 2719744);
    unsigned short* x_bf = (unsigned short*)(ws + 7962624);
    unsigned short* h    = (unsigned short*)(ws + 41517056);

    hipMemsetAsync(pooled, 0, Bb * Ww * sizeof(float), stream);
    mask_expand_kernel<<<1, 256, 0, stream>>>(mask, maskf);
    wconv_kernel<<<1024, 256, 0, stream>>>(conv_w, w_bf);
    offsets_kernel<<<BL, 256, 0, stream>>>(x, w_off, b_off, x_bf, idx0, idx1, w0a, w1a);
    gemm_kernel<<<dim3(8, 128), 256, 0, stream>>>(x_bf, w_bf, idx0, idx1, w0a, w1a, conv_b, h);
    lnpool_kernel<<<128, 256, 0, stream>>>(h, gamma, beta, maskf, pooled);
    final_kernel<<<8, 256, 0, stream>>>(pooled, maskf, proj_w, proj_b, out);
}